// Round 1
// baseline (541.636 us; speedup 1.0000x reference)
//
#include <hip/hip_runtime.h>
#include <hip/hip_bf16.h>

typedef __hip_bfloat16 bf16;
typedef short bf16x8 __attribute__((ext_vector_type(8)));
typedef float f32x4  __attribute__((ext_vector_type(4)));

#define ROWS 53176    // B * L_TOTAL
#define LTOT 13294

__device__ __forceinline__ float b2f(bf16 v) { return __bfloat162float(v); }

__device__ __forceinline__ void gl2lds16(const void* g, void* l) {
    __builtin_amdgcn_global_load_lds(
        (const __attribute__((address_space(1))) unsigned*)g,
        (__attribute__((address_space(3))) unsigned*)l, 16, 0, 0);
}

// ============ B-stationary GEMM: K=256 entirely in LDS, barrier-free K-loop ====
// C[M,N] = A[M,256] @ Bt[N,256]^T + bias (opt ReLU).  Block: 256 thr, 4 waves,
// 256 rows x 128 cols per block.  B panel 128x256 bf16 = 64KB LDS staged ONCE
// (linear 64KB copy, T2 XOR-swizzle applied on the pre-swizzled global source).
// A fragments stream global->reg (16B/lane, full 64B-line use across quads).
template<bool RELU>
__global__ __launch_bounds__(256, 2)
void gemm_bs_n(const bf16* __restrict__ A, const bf16* __restrict__ Bt,
               const float* __restrict__ bias, bf16* __restrict__ C,
               int M, int N)
{
    __shared__ __align__(16) char Bsb[65536];   // 128 rows x 256 K x 2B
    const int tid  = threadIdx.x;
    const int wave = tid >> 6, lane = tid & 63;
    const int l15 = lane & 15, quad = lane >> 4;
    const int swz = (lane & 7) << 4;
    const int m0 = blockIdx.y * 256, n0 = blockIdx.x * 128;

    // ---- stage full B panel (pure linear 64KB copy, source pre-swizzled) ----
    const char* Btb = (const char*)(Bt + (size_t)n0 * 256);
#pragma unroll
    for (int it = 0; it < 16; ++it) {
        int c = it * 256 + tid;                       // 16B chunk index
        int srcoff = (c * 16) ^ (((c >> 5) & 7) << 4);
        gl2lds16(Btb + srcoff, Bsb + (it * 256 + wave * 64) * 16);
    }

    // ---- A row pointers (clamped) ----
    const bf16* aptr[4];
#pragma unroll
    for (int i = 0; i < 4; ++i) {
        int r = m0 + wave * 64 + i * 16 + l15;
        if (r > M - 1) r = M - 1;
        aptr[i] = A + (size_t)r * 256;
    }

    f32x4 acc[4][8];
#pragma unroll
    for (int i = 0; i < 4; ++i)
#pragma unroll
        for (int j = 0; j < 8; ++j) acc[i][j] = (f32x4){0.f, 0.f, 0.f, 0.f};

    __syncthreads();   // B panel ready; no barriers from here on

#pragma unroll
    for (int kc = 0; kc < 8; ++kc) {                  // kk = kc*32
        bf16x8 af[4], bfr[8];
#pragma unroll
        for (int i = 0; i < 4; ++i)
            af[i] = *(const bf16x8*)(aptr[i] + kc * 32 + quad * 8);
#pragma unroll
        for (int j = 0; j < 8; ++j) {
            int boff = ((j * 16 + l15) * 512 + kc * 64 + quad * 16) ^ swz;
            bfr[j] = *(const bf16x8*)&Bsb[boff];
        }
#pragma unroll
        for (int i = 0; i < 4; ++i)
#pragma unroll
            for (int j = 0; j < 8; ++j)
                acc[i][j] = __builtin_amdgcn_mfma_f32_16x16x32_bf16(bfr[j], af[i], acc[i][j], 0, 0, 0);
    }

    // ---- epilogue (identical layout mapping to verified kernel) ----
    float4 b4[8];
#pragma unroll
    for (int j = 0; j < 8; ++j)
        b4[j] = *(const float4*)&bias[n0 + j * 16 + quad * 4];

#pragma unroll
    for (int i = 0; i < 4; ++i) {
        int gm = m0 + wave * 64 + i * 16 + l15;
        if (gm >= M) continue;
#pragma unroll
        for (int j = 0; j < 8; ++j) {
            int gn = n0 + j * 16 + quad * 4;
            union { bf16 h[4]; uint2 u2; } pk;
#pragma unroll
            for (int r = 0; r < 4; ++r) {
                float v = acc[i][j][r] + ((const float*)&b4[j])[r];
                if (RELU) v = fmaxf(v, 0.f);
                pk.h[r] = __float2bfloat16(v);
            }
            *(uint2*)&C[(size_t)gm * N + gn] = pk.u2;
        }
    }
}

// ============ B-stationary GEMM + fused LayerNorm, N=256 full per block =======
// out = LN( A[M,K] @ Bt[256,K]^T + bias + res ).  Block: 256 thr, 4 waves,
// 128 rows/block, each wave owns 32 rows x ALL 256 cols -> LN reduce is two
// shfl_xor (no LDS atomics).  B staged in 64KB chunks (256 x BK=128).
template<typename OT, int K>
__global__ __launch_bounds__(256, 2)
void gemm_bs_ln(const bf16* __restrict__ A, const bf16* __restrict__ Bt,
                const float* __restrict__ bias, const bf16* __restrict__ res,
                OT* __restrict__ C, const float* __restrict__ gam,
                const float* __restrict__ bet, int M)
{
    __shared__ __align__(16) char Bsb[65536];   // 256 rows x 128 K x 2B
    const int tid  = threadIdx.x;
    const int wave = tid >> 6, lane = tid & 63;
    const int l15 = lane & 15, quad = lane >> 4;
    const int swz = (lane & 7) << 4;
    const int m0 = blockIdx.x * 128;

    const bf16* aptr[2];
#pragma unroll
    for (int i = 0; i < 2; ++i) {
        int r = m0 + wave * 32 + i * 16 + l15;
        if (r > M - 1) r = M - 1;
        aptr[i] = A + (size_t)r * K;
    }

    f32x4 acc[2][16];
#pragma unroll
    for (int i = 0; i < 2; ++i)
#pragma unroll
        for (int j = 0; j < 16; ++j) acc[i][j] = (f32x4){0.f, 0.f, 0.f, 0.f};

    for (int kc = 0; kc < K / 128; ++kc) {
        // stage B[0:256][kc*128 : +128], source pre-swizzled
#pragma unroll
        for (int it = 0; it < 16; ++it) {
            int c = it * 256 + tid;
            int row = c >> 4, col = c & 15;
            size_t srcoff = (size_t)row * (K * 2) + kc * 256
                          + ((col * 16) ^ ((row & 7) << 4));
            gl2lds16((const char*)Bt + srcoff, Bsb + (it * 256 + wave * 64) * 16);
        }
        __syncthreads();
#pragma unroll
        for (int t = 0; t < 4; ++t) {                 // kkl = t*32
            bf16x8 af[2], bfr[16];
#pragma unroll
            for (int i = 0; i < 2; ++i)
                af[i] = *(const bf16x8*)(aptr[i] + kc * 128 + t * 32 + quad * 8);
#pragma unroll
            for (int j = 0; j < 16; ++j) {
                int boff = ((j * 16 + l15) * 256 + t * 64 + quad * 16) ^ swz;
                bfr[j] = *(const bf16x8*)&Bsb[boff];
            }
#pragma unroll
            for (int i = 0; i < 2; ++i)
#pragma unroll
                for (int j = 0; j < 16; ++j)
                    acc[i][j] = __builtin_amdgcn_mfma_f32_16x16x32_bf16(bfr[j], af[i], acc[i][j], 0, 0, 0);
        }
        __syncthreads();
    }

    // ---- fused residual + LayerNorm epilogue, fully wave-local ----
#pragma unroll
    for (int i = 0; i < 2; ++i) {
        int gm = m0 + wave * 32 + i * 16 + l15;
        bool valid = gm < M;
        float lsum = 0.f, lsq = 0.f;
#pragma unroll
        for (int j = 0; j < 16; ++j) {
            int gn = j * 16 + quad * 4;
            float4 b4 = *(const float4*)&bias[gn];
            float r4[4] = {0.f, 0.f, 0.f, 0.f};
            if (valid) {
                uint2 ru = *(const uint2*)&res[(size_t)gm * 256 + gn];
                const bf16* rh = (const bf16*)&ru;
#pragma unroll
                for (int r = 0; r < 4; ++r) r4[r] = b2f(rh[r]);
            }
#pragma unroll
            for (int r = 0; r < 4; ++r) {
                float v = acc[i][j][r] + ((const float*)&b4)[r] + r4[r];
                acc[i][j][r] = v;
                lsum += v;
                lsq  += v * v;
            }
        }
#pragma unroll
        for (int mask = 16; mask <= 32; mask <<= 1) {
            lsum += __shfl_xor(lsum, mask);
            lsq  += __shfl_xor(lsq, mask);
        }
        if (!valid) continue;
        float mean = lsum * (1.f / 256.f);
        float var  = lsq * (1.f / 256.f) - mean * mean;
        float rstd = rsqrtf(fmaxf(var, 0.f) + 1e-5f);
#pragma unroll
        for (int j = 0; j < 16; ++j) {
            int gn = j * 16 + quad * 4;
            float4 g4  = *(const float4*)&gam[gn];
            float4 be4 = *(const float4*)&bet[gn];
            if constexpr (sizeof(OT) == 2) {
                union { bf16 h[4]; uint2 u2; } pk;
#pragma unroll
                for (int r = 0; r < 4; ++r)
                    pk.h[r] = __float2bfloat16((acc[i][j][r] - mean) * rstd *
                              ((const float*)&g4)[r] + ((const float*)&be4)[r]);
                *(uint2*)&((bf16*)C)[(size_t)gm * 256 + gn] = pk.u2;
            } else {
                float4 o;
#pragma unroll
                for (int r = 0; r < 4; ++r)
                    ((float*)&o)[r] = (acc[i][j][r] - mean) * rstd *
                              ((const float*)&g4)[r] + ((const float*)&be4)[r];
                *(float4*)&((float*)C)[(size_t)gm * 256 + gn] = o;
            }
        }
    }
}

// ============ casts ============
__global__ void cast_qs_kernel(const float* __restrict__ s, const float* __restrict__ p,
                               bf16* __restrict__ sb, bf16* __restrict__ qb, int n4)
{
    int i = blockIdx.x * 256 + threadIdx.x;
    if (i >= n4) return;
    float4 sv = ((const float4*)s)[i];
    float4 pv = ((const float4*)p)[i];
    union { bf16 h[4]; uint2 u; } a, b;
    a.h[0] = __float2bfloat16(sv.x); a.h[1] = __float2bfloat16(sv.y);
    a.h[2] = __float2bfloat16(sv.z); a.h[3] = __float2bfloat16(sv.w);
    b.h[0] = __float2bfloat16(sv.x + pv.x); b.h[1] = __float2bfloat16(sv.y + pv.y);
    b.h[2] = __float2bfloat16(sv.z + pv.z); b.h[3] = __float2bfloat16(sv.w + pv.w);
    ((uint2*)sb)[i] = a.u;
    ((uint2*)qb)[i] = b.u;
}

__global__ void wcast_all(const float* __restrict__ Wval, const float* __restrict__ Woff,
                          const float* __restrict__ Wattn, const float* __restrict__ Wout,
                          const float* __restrict__ W1, const float* __restrict__ W2,
                          const float* __restrict__ boff, const float* __restrict__ battn,
                          bf16* __restrict__ Wval_t, bf16* __restrict__ Wcat_t,
                          bf16* __restrict__ Wout_t, bf16* __restrict__ W1_t,
                          bf16* __restrict__ W2_t, float* __restrict__ bcat)
{
    int e = blockIdx.x * 256 + threadIdx.x;
    if (e < 384) bcat[e] = (e < 256) ? boff[e] : battn[e - 256];
    if (e < 65536) {
        int n = e >> 8, k = e & 255;
        Wval_t[e] = __float2bfloat16(Wval[k * 256 + n]);
    } else if (e < 163840) {
        int i = e - 65536; int n = i >> 8, k = i & 255;
        float w = (n < 256) ? Woff[k * 256 + n] : Wattn[k * 128 + (n - 256)];
        Wcat_t[i] = __float2bfloat16(w);
    } else if (e < 229376) {
        int i = e - 163840; int n = i >> 8, k = i & 255;
        Wout_t[i] = __float2bfloat16(Wout[k * 256 + n]);
    } else if (e < 491520) {
        int i = e - 229376; int n = i >> 8, k = i & 255;
        W1_t[i] = __float2bfloat16(W1[k * 1024 + n]);
    } else if (e < 753664) {
        int i = e - 491520; int n = i >> 10, k = i & 1023;
        W2_t[i] = __float2bfloat16(W2[k * 256 + n]);
    }
}

// ============ deformable sampling + fused softmax (16-lane groups) ============
__global__ __launch_bounds__(256)
void sample_kernel(const bf16* __restrict__ v, const bf16* __restrict__ ocat,
                   const float* __restrict__ ref, bf16* __restrict__ samp)
{
    __shared__ int4 tab[16][33];
    const int tid = threadIdx.x;
    const int grp = tid >> 4, lane = tid & 15;
    const int gidx = blockIdx.x * 16 + grp;
    const int h = gidx & 7, bq = gidx >> 3, b = bq / LTOT;

    {   // phase A: point p = lane; softmax over 16 lanes
        const int p = lane, l = p >> 2, pp = p & 3;
        const int W = (l == 0) ? 100 : (l == 1) ? 50 : (l == 2) ? 25 : 13;
        const int S = (l == 0) ? 0 : (l == 1) ? 10000 : (l == 2) ? 12500 : 13125;
        const float fW = (float)W;
        float rx = ref[(size_t)bq * 8 + l * 2 + 0];
        float ry = ref[(size_t)bq * 8 + l * 2 + 1];
        const bf16* ob = ocat + (size_t)bq * 384;
        float ox = b2f(ob[h * 32 + l * 8 + pp * 2 + 0]);
        float oy = b2f(ob[h * 32 + l * 8 + pp * 2 + 1]);
        float lg = b2f(ob[256 + h * 16 + p]);
        float m = lg;
#pragma unroll
        for (int mask = 1; mask <= 8; mask <<= 1) m = fmaxf(m, __shfl_xor(m, mask));
        float ev = __expf(lg - m);
        float s = ev;
#pragma unroll
        for (int mask = 1; mask <= 8; mask <<= 1) s += __shfl_xor(s, mask);
        float wgt = ev / s;

        float x = fmaf(rx, fW, ox - 0.5f);
        float y = fmaf(ry, fW, oy - 0.5f);   // H == W at every level
        float x0f = floorf(x), y0f = floorf(y);
        float lx = x - x0f, ly = y - y0f;
        int x0 = (int)x0f, y0 = (int)y0f;
        float tw[4] = {(1.f - lx) * (1.f - ly), lx * (1.f - ly),
                       (1.f - lx) * ly,         lx * ly};
        const int base = (b * LTOT + S) * 512 + h * 64;
        int  o[4]; float w[4];
#pragma unroll
        for (int t = 0; t < 4; ++t) {
            int xi = x0 + (t & 1), yi = y0 + (t >> 1);
            bool ok = (xi >= 0) & (xi < W) & (yi >= 0) & (yi < W);
            o[t] = ok ? base + (yi * W + xi) * 512 : 0;
            w[t] = ok ? wgt * tw[t] : 0.f;
        }
        tab[grp][p * 2 + 0] = make_int4(o[0], __float_as_int(w[0]), o[1], __float_as_int(w[1]));
        tab[grp][p * 2 + 1] = make_int4(o[2], __float_as_int(w[2]), o[3], __float_as_int(w[3]));
    }
    __syncthreads();

    const int lofs = lane * 4;
    const char* vc = (const char*)v;
    float a0 = 0.f, a1 = 0.f;
#pragma unroll 4
    for (int e2 = 0; e2 < 32; ++e2) {
        int4 q = tab[grp][e2];
        unsigned u0 = *(const unsigned*)(vc + (size_t)(unsigned)(q.x + lofs));
        unsigned u1 = *(const unsigned*)(vc + (size_t)(unsigned)(q.z + lofs));
        float w0 = __int_as_float(q.y), w1 = __int_as_float(q.w);
        a0 += w0 * __uint_as_float(u0 << 16);
        a1 += w0 * __uint_as_float(u0);   // low-16 mantissa noise, within budget
        a0 += w1 * __uint_as_float(u1 << 16);
        a1 += w1 * __uint_as_float(u1);
    }
    union { struct { bf16 a, b; } h2; unsigned u; } r;
    r.h2.a = __float2bfloat16(a0);
    r.h2.b = __float2bfloat16(a1);
    *(unsigned*)((char*)samp + (size_t)gidx * 64 + lane * 4) = r.u;
}

extern "C" void kernel_launch(void* const* d_in, const int* in_sizes, int n_in,
                              void* d_out, int out_size, void* d_ws, size_t ws_size,
                              hipStream_t stream)
{
    const float* src     = (const float*)d_in[0];
    const float* pos     = (const float*)d_in[1];
    const float* ref     = (const float*)d_in[2];
    const float* W_off   = (const float*)d_in[5];
    const float* b_off   = (const float*)d_in[6];
    const float* W_attn  = (const float*)d_in[7];
    const float* b_attn  = (const float*)d_in[8];
    const float* W_val   = (const float*)d_in[9];
    const float* b_val   = (const float*)d_in[10];
    const float* W_out   = (const float*)d_in[11];
    const float* b_out   = (const float*)d_in[12];
    const float* ln_sa_g = (const float*)d_in[13];
    const float* ln_sa_b = (const float*)d_in[14];
    const float* W1      = (const float*)d_in[15];
    const float* b1      = (const float*)d_in[16];
    const float* W2      = (const float*)d_in[17];
    const float* b2      = (const float*)d_in[18];
    const float* ln_ff_g = (const float*)d_in[19];
    const float* ln_ff_b = (const float*)d_in[20];

    char* ws = (char*)d_ws;
    // ws layout:
    //   sb   [0, 27226112)          cast -> G1(A), G6(residual)
    //   qb   [27226112, 54452224)   cast -> G23;  then samp (sample -> G6)
    //   vbuf [54452224, 81678336)   G1 -> sample
    //   ocat [81678336, 122517504)  G23 -> sample
    //   xb16 [122517504, 149743616) G6 -> G8, G9(residual)
    //   wts  [149743616, 151252480)
    //   hbuf [0, 108904448)         G8 -> G9 (overlaps sb/qb/vbuf/ocat-head, all dead)
    bf16* sb     = (bf16*)(ws);
    bf16* qb     = (bf16*)(ws + 27226112);
    bf16* samp   = (bf16*)(ws + 27226112);
    bf16* vbuf   = (bf16*)(ws + 54452224);
    bf16* ocat   = (bf16*)(ws + 81678336);
    bf16* xb16   = (bf16*)(ws + 122517504);
    bf16* hbuf   = (bf16*)(ws);
    bf16* Wval_t = (bf16*)(ws + 149743616);
    bf16* Wcat_t = (bf16*)(ws + 149874688);
    float* bcat  = (float*)(ws + 150071296);
    bf16* Wout_t = (bf16*)(ws + 150072832);
    bf16* W1_t   = (bf16*)(ws + 150203904);
    bf16* W2_t   = (bf16*)(ws + 150728192);
    float* outf  = (float*)d_out;

    dim3 blk(256);

    cast_qs_kernel<<<dim3((ROWS * 64 + 255) / 256), blk, 0, stream>>>(src, pos, sb, qb, ROWS * 64);
    wcast_all<<<dim3(2944), blk, 0, stream>>>(W_val, W_off, W_attn, W_out, W1, W2,
                                              b_off, b_attn,
                                              Wval_t, Wcat_t, Wout_t, W1_t, W2_t, bcat);

    // v = src @ W_val + b_val
    gemm_bs_n<false><<<dim3(2, 208), blk, 0, stream>>>(sb, Wval_t, b_val, vbuf, ROWS, 256);
    // [off | attn logits] = q @ Wcat + bcat
    gemm_bs_n<false><<<dim3(3, 208), blk, 0, stream>>>(qb, Wcat_t, bcat, ocat, ROWS, 384);
    // softmax + sampling
    sample_kernel<<<dim3(ROWS * 8 / 16), blk, 0, stream>>>(vbuf, ocat, ref, samp);
    // x = LN(samp @ W_out + b_out + sb)
    gemm_bs_ln<bf16, 256><<<dim3(416), blk, 0, stream>>>(
        samp, Wout_t, b_out, sb, xb16, ln_sa_g, ln_sa_b, ROWS);
    // h = relu(x @ W1 + b1)
    gemm_bs_n<true><<<dim3(8, 208), blk, 0, stream>>>(xb16, W1_t, b1, hbuf, ROWS, 1024);
    // out = LN(h @ W2 + b2 + x)
    gemm_bs_ln<float, 1024><<<dim3(416), blk, 0, stream>>>(
        hbuf, W2_t, b2, xb16, outf, ln_ff_g, ln_ff_b, ROWS);
}